// Round 4
// baseline (358.959 us; speedup 1.0000x reference)
//
#include <hip/hip_runtime.h>

typedef unsigned short u16;
typedef unsigned int   u32;
typedef unsigned long long u64;

typedef __attribute__((ext_vector_type(8))) __bf16 bf16x8;
typedef __attribute__((ext_vector_type(4))) float  floatx4;

#define D_MODEL 1024
#define L_SEQ   4096
#define BATCH   4
#define N_HEADS 16
#define D_HEAD  64
#define CHUNK   128
#define N_CHUNKS 32
#define M_ROWS  (BATCH * L_SEQ)   // 16384
#define NQKV    3072              // fused q|k|v output width

// ---------- bf16 helpers ----------
__device__ __forceinline__ float bf2f(u16 u) {
    union { u32 i; float f; } x; x.i = ((u32)u) << 16; return x.f;
}
__device__ __forceinline__ u16 f2bf(float f) {
    union { u32 i; float fl; } x; x.fl = f;
    u32 i = x.i;
    u32 r = (i + 0x7FFFu + ((i >> 16) & 1u)) >> 16;
    return (u16)r;
}

__device__ __forceinline__ float load_decay(const void* dec, int h) {
    const u16* d16 = (const u16*)dec;
    const float as_bf = bf2f(d16[0]);
    if (as_bf > 1e-6f && as_bf <= 1.0001f) return bf2f(d16[h]);
    return ((const float*)dec)[h];
}

// direct global->LDS 16B async copy. HW semantics: per-lane global addr;
// LDS dest = wave-uniform base + lane*16 (m97/m104).
__device__ __forceinline__ void gload_lds16(const u16* g, u16* l) {
    __builtin_amdgcn_global_load_lds(
        (const __attribute__((address_space(1))) u32*)g,
        (__attribute__((address_space(3))) u32*)l, 16, 0, 0);
}

// ---------- dtype detection: flags[0]=x is fp32, flags[1]=W is fp32 --------
__global__ void detect_dtypes(const void* __restrict__ x,
                              const void* __restrict__ w,
                              int* __restrict__ flags) {
    const int lane = threadIdx.x;                 // 64 threads
    const u16* x16 = (const u16*)x;
    const u16* w16 = (const u16*)w;
    const float vx = fabsf(bf2f(x16[lane]));
    const float vw = fabsf(bf2f(w16[lane]));
    const bool ox = (vx != 0.0f) && (vx > 1e4f || vx < 1e-4f);
    const bool ow = (vw != 0.0f) && (vw > 1e4f || vw < 1e-4f);
    const u64 bx = __ballot(ox);
    const u64 bw = __ballot(ow);
    if (lane == 0) {
        flags[0] = (__popcll(bx) >= 8) ? 1 : 0;
        flags[1] = (__popcll(bw) >= 8) ? 1 : 0;
    }
}

// ---------- x -> canonical bf16 buffer ----------
__global__ __launch_bounds__(256)
void convert_x(const void* __restrict__ x, const int* __restrict__ flags,
               u16* __restrict__ xb) {
    const int mode = flags[0];
    const size_t i0 = ((size_t)blockIdx.x * 256 + threadIdx.x) * 8;
    if (mode) {
        const float* xf = (const float*)x;
        u16 tmp[8];
#pragma unroll
        for (int j = 0; j < 8; j++) tmp[j] = f2bf(xf[i0 + j]);
        *(uint4*)(xb + i0) = *(const uint4*)tmp;
    } else {
        *(uint4*)(xb + i0) = *(const uint4*)((const u16*)x + i0);
    }
}

// ---------- weight transpose: T[n][k] = bf16(W[k][n]), dual dtype ----------
__global__ __launch_bounds__(256)
void transpose4(const void* __restrict__ W0, const void* __restrict__ W1,
                const void* __restrict__ W2, const void* __restrict__ W3,
                const int* __restrict__ flags,
                u16* __restrict__ T0, u16* __restrict__ T1,
                u16* __restrict__ T2, u16* __restrict__ T3) {
    __shared__ u16 tile[32][33];
    const int mode = flags[1];
    const void* src; u16* dst;
    switch (blockIdx.z) {
        case 0: src = W0; dst = T0; break;
        case 1: src = W1; dst = T1; break;
        case 2: src = W2; dst = T2; break;
        default: src = W3; dst = T3; break;
    }
    const int tx = threadIdx.x & 31, ty = threadIdx.x >> 5;  // ty in 0..7
    const int x0 = blockIdx.x * 32, y0 = blockIdx.y * 32;
#pragma unroll
    for (int i = 0; i < 32; i += 8) {
        const size_t idx = (size_t)(y0 + ty + i) * D_MODEL + x0 + tx;
        tile[ty + i][tx] = mode ? f2bf(((const float*)src)[idx])
                                : ((const u16*)src)[idx];
    }
    __syncthreads();
#pragma unroll
    for (int i = 0; i < 32; i += 8)
        dst[(size_t)(x0 + ty + i) * D_MODEL + y0 + tx] = tile[tx][ty + i];
}

// ---------- bias concat: dst[0..4096) = bf16(bq|bk|bv|bo), dual dtype ------
__global__ __launch_bounds__(256)
void concat_bias(const void* __restrict__ bq, const void* __restrict__ bk,
                 const void* __restrict__ bv, const void* __restrict__ bo,
                 const int* __restrict__ flags, u16* __restrict__ dst) {
    const int i = blockIdx.x * 256 + threadIdx.x;  // 0..4095
    const int mode = flags[1];
    const int which = i >> 10, idx = i & 1023;
    const void* src = (which == 0) ? bq : (which == 1) ? bk
                      : (which == 2) ? bv : bo;
    dst[i] = mode ? f2bf(((const float*)src)[idx]) : ((const u16*)src)[idx];
}

// ---------- 256x256 software-pipelined GEMM (m201-faithful schedule) -------
// C = A[16384,1024] . Bt[N,1024]^T + bias.
// 512 threads = 8 waves (2M x 4N), BK=64, 2 LDS buffers (128 KiB dynamic).
// KEY CHANGE vs R1-R3: fragments are ds-read ONE PHASE BEFORE their MFMA
// consumes them (4 persistent frag sets af0/af1/bb0/bb1), so the post-
// barrier lgkm drain is hidden under the previous quadrant's MFMA cluster.
// One half-tile staged per phase targeting kt+2 (4-7 phase flight);
// counted vmcnt(8) twice per K-tile, never 0 until the tail. All ds_reads
// placed AFTER a barrier that follows every wave's vmcnt-drain of the
// region's stage (cross-wave visibility is barrier-published).
//
// Steady-state per-wave outstanding-load ledger (2 loads per half-tile):
//   p0: stage B1(kt+1); vmcnt(8) drains A1(kt),B1(kt); BAR; ds bb1<-B1(kt)
//   p1: stage A0(kt+2);                               BAR; ds af1<-A1(kt)
//   p2: stage B0(kt+2); vmcnt(8) drains A0,B0(kt+1);  BAR; (no ds)
//   p3: stage A1(kt+2);                               BAR; ds af0<-A0(kt+1),
//                                                          bb0<-B0(kt+1)
// Quadrant order (0,0)(0,1)(1,0)(1,1); each frag set's last use precedes
// its reload; each staged region's last LDS read is >=1 barrier before the
// overwriting stage is issued.
template <typename OutT>
__global__ __launch_bounds__(512, 2)
void gemm_256(const u16* __restrict__ A, const u16* __restrict__ Bt,
              const u16* __restrict__ bias, OutT* __restrict__ C, int N) {
    extern __shared__ u16 lds[];           // 131072 B: buf{0,1} x (A|B)
    constexpr int K  = 1024;
    constexpr int NT = K / 64;             // 16 K-tiles

    const int t = threadIdx.x;
    const int lane = t & 63, w = t >> 6;
    const int col16 = lane & 15, quad = lane >> 4;
    const int wm = w >> 2, wn = w & 3;     // wave grid 2M x 4N

    // L2-aware decode (bid -> XCD assumed bid%8 round-robin):
    // m-panel = (bid&7)*8 + ((bid>>3)&7)  -> 8 panels per XCD (4MB = its L2)
    const int bid = blockIdx.x;
    const int m0 = (((bid & 7) << 3) + ((bid >> 3) & 7)) * 256;
    const int n0 = (bid >> 6) * 256;

    // staging: 1 gload inst/wave = 1 KB = 8 rows of 128 B; src pre-swizzled
    const int rl = lane >> 3;
    const int sseg = (lane & 7) ^ rl;

    // STAGE(G, kt, isB, half): stage 128 rows x 64 k (16 KB) = 2 gloads/wave
    auto STAGE = [&](const u16* __restrict__ G, int kt, int isB, int half) {
        u16* l0 = lds + (kt & 1) * 32768 + isB * 16384
                      + (half * 128 + w * 8) * 64;
        const u16* g0 = G + (size_t)((isB ? n0 : m0) + half * 128 + w * 8 + rl) * K
                          + kt * 64 + sseg * 8;
        gload_lds16(g0, l0);
        gload_lds16(g0 + (size_t)64 * K, l0 + 64 * 64);
    };

    bf16x8 af0[4][2], af1[4][2], bb0[2][2], bb1[2][2];
    floatx4 acc[2][2][4][2];               // [mh][nh][i][j]
#pragma unroll
    for (int a = 0; a < 2; a++)
#pragma unroll
        for (int b = 0; b < 2; b++)
#pragma unroll
            for (int i = 0; i < 4; i++)
#pragma unroll
                for (int j = 0; j < 2; j++)
                    acc[a][b][i][j] = floatx4{0.f, 0.f, 0.f, 0.f};

    // zero-conflict fragment reads (R1-measured): seg = (k0*4+quad)^(row&7)
    auto LDA = [&](bf16x8 (&af)[4][2], int kt, int mh) {
        const u16* tb = lds + (kt & 1) * 32768;
#pragma unroll
        for (int i = 0; i < 4; i++) {
            const int row = mh * 128 + wm * 64 + i * 16 + col16;
#pragma unroll
            for (int k0 = 0; k0 < 2; k0++) {
                const int seg = (k0 * 4 + quad) ^ (row & 7);
                af[i][k0] = *(const bf16x8*)(tb + row * 64 + seg * 8);
            }
        }
    };
    auto LDB = [&](bf16x8 (&bb)[2][2], int kt, int nh) {
        const u16* tb = lds + (kt & 1) * 32768 + 16384;
#pragma unroll
        for (int j = 0; j < 2; j++) {
            const int row = nh * 128 + wn * 32 + j * 16 + col16;
#pragma unroll
            for (int k0 = 0; k0 < 2; k0++) {
                const int seg = (k0 * 4 + quad) ^ (row & 7);
                bb[j][k0] = *(const bf16x8*)(tb + row * 64 + seg * 8);
            }
        }
    };

#define MMQ(MH, NH, AF, BB)                                                   \
    do {                                                                      \
        __builtin_amdgcn_s_setprio(1);                                        \
        _Pragma("unroll")                                                     \
        for (int i = 0; i < 4; i++)                                           \
            _Pragma("unroll")                                                 \
            for (int j = 0; j < 2; j++)                                       \
                _Pragma("unroll")                                             \
                for (int k0 = 0; k0 < 2; k0++)                                \
                    acc[MH][NH][i][j] =                                       \
                        __builtin_amdgcn_mfma_f32_16x16x32_bf16(              \
                            AF[i][k0], BB[j][k0], acc[MH][NH][i][j], 0, 0, 0);\
        __builtin_amdgcn_s_setprio(0);                                        \
    } while (0)

    // ---- prologue: tile0 fully + A0,B0,A1 of tile1 = 14 loads in flight ---
    STAGE(A, 0, 0, 0); STAGE(Bt, 0, 1, 0); STAGE(A, 0, 0, 1); STAGE(Bt, 0, 1, 1);
    STAGE(A, 1, 0, 0); STAGE(Bt, 1, 1, 0); STAGE(A, 1, 0, 1);
    asm volatile("s_waitcnt vmcnt(8)" ::: "memory");  // A0(0),B0(0),A1(0) in
    __builtin_amdgcn_s_barrier();
    LDA(af0, 0, 0); LDB(bb0, 0, 0);

#pragma unroll 2
    for (int kt = 0; kt < NT; ++kt) {
        // ---- p0: quadrant (0,0) ----
        if (kt + 1 < NT) STAGE(Bt, kt + 1, 1, 1);
        if (kt + 1 < NT) asm volatile("s_waitcnt vmcnt(8)" ::: "memory");
        else             asm volatile("s_waitcnt vmcnt(0)" ::: "memory");
        __builtin_amdgcn_s_barrier();
        LDB(bb1, kt, 1);                   // consumed at p1
        MMQ(0, 0, af0, bb0);
        // ---- p1: quadrant (0,1) ----
        if (kt + 2 < NT) STAGE(A, kt + 2, 0, 0);
        __builtin_amdgcn_s_barrier();
        LDA(af1, kt, 1);                   // consumed at p2
        MMQ(0, 1, af0, bb1);
        // ---- p2: quadrant (1,0) ----
        if (kt + 2 < NT) STAGE(Bt, kt + 2, 1, 0);
        if (kt + 2 < NT)      asm volatile("s_waitcnt vmcnt(8)" ::: "memory");
        else if (kt + 2 == NT) asm volatile("s_waitcnt vmcnt(4)" ::: "memory");
        __builtin_amdgcn_s_barrier();
        MMQ(1, 0, af1, bb0);
        // ---- p3: quadrant (1,1) ----
        if (kt + 2 < NT) STAGE(A, kt + 2, 0, 1);
        __builtin_amdgcn_s_barrier();
        if (kt + 1 < NT) { LDA(af0, kt + 1, 0); LDB(bb0, kt + 1, 0); }
        MMQ(1, 1, af1, bb1);
    }
#undef MMQ

    // ---- epilogue. 16x16 C/D layout: col=lane&15, row=quad*4+reg ----
    if constexpr (sizeof(OutT) == 2) {
        // repack through LDS (now free) for coalesced 16B stores.
        u16* sm = lds;
#pragma unroll
        for (int mh = 0; mh < 2; mh++) {
            __syncthreads();
#pragma unroll
            for (int nh = 0; nh < 2; nh++)
#pragma unroll
                for (int j = 0; j < 2; j++) {
                    const int lcol = nh * 128 + wn * 32 + j * 16 + col16;
                    const float bsf = bf2f(bias[n0 + lcol]);
#pragma unroll
                    for (int i = 0; i < 4; i++)
#pragma unroll
                        for (int r = 0; r < 4; r++)
                            sm[(wm * 64 + i * 16 + quad * 4 + r) * 264 + lcol] =
                                f2bf(acc[mh][nh][i][j][r] + bsf);
                }
            __syncthreads();
            // 128 rows x 32 uint4-segments = 4096 stores, 8 per thread
#pragma unroll
            for (int it = 0; it < 8; it++) {
                const int lin = it * 512 + t;
                const int row = lin >> 5, seg = lin & 31;
                *(uint4*)&C[(size_t)(m0 + mh * 128 + row) * N + n0 + seg * 8] =
                    *(const uint4*)&sm[row * 264 + seg * 8];
            }
        }
    } else {
#pragma unroll
        for (int mh = 0; mh < 2; mh++)
#pragma unroll
            for (int nh = 0; nh < 2; nh++)
#pragma unroll
                for (int j = 0; j < 2; j++) {
                    const int gcol = n0 + nh * 128 + wn * 32 + j * 16 + col16;
                    const float bsf = bf2f(bias[gcol]);
#pragma unroll
                    for (int i = 0; i < 4; i++) {
                        const int gr = m0 + mh * 128 + wm * 64 + i * 16 + quad * 4;
#pragma unroll
                        for (int r = 0; r < 4; r++)
                            C[(size_t)(gr + r) * N + gcol] =
                                acc[mh][nh][i][j][r] + bsf;
                    }
                }
    }
}

// ---------- retention via MFMA: one block per (chunk, b, h) tile -----------
// Reads fused qkv [16384][3072] (q|k|v); writes att [16384][1024].
#define QS 72
#define PS 136
#define VT 136
#define KS_OFF (128 * QS)

__global__ __launch_bounds__(256)
void retention_mfma(const u16* __restrict__ qkv, const void* __restrict__ dec,
                    u16* __restrict__ att) {
    __shared__ u16 qk[2 * 128 * QS];   // Qs | Ks ; later overlaid by Ps
    __shared__ u16 vt[64 * VT];        // V^T: [d][key]
    __shared__ float kp[64], vp[64], s0f[128];
    u16* Ps = qk;

    const int c = blockIdx.x, b = blockIdx.y, h = blockIdx.z;
    const int t = threadIdx.x;
    const int lane = t & 63, w = t >> 6;
    const int col16 = lane & 15, quad = lane >> 4;
    const int R0 = w * 32;
    const size_t base  = ((size_t)b * L_SEQ) * NQKV + h * D_HEAD;
    const size_t gbase = base + (size_t)(c * CHUNK) * NQKV;
    const size_t obase = (((size_t)b * L_SEQ) + c * CHUNK) * D_MODEL + h * D_HEAD;

    // ---- stage Q, K (row-major) and V (transposed) ----
#pragma unroll
    for (int it = 0; it < 4; it++) {
        const int i = it * 256 + t;
        const int row = i >> 3, seg = i & 7;
        const size_t go = gbase + (size_t)row * NQKV + seg * 8;
        *(uint4*)&qk[row * QS + seg * 8]          = *(const uint4*)(qkv + go);
        *(uint4*)&qk[KS_OFF + row * QS + seg * 8] = *(const uint4*)(qkv + go + 1024);
    }
#pragma unroll
    for (int it = 0; it < 4; it++) {
        const int i = it * 256 + t;
        const int key = i & 127, dseg = i >> 7;
        u16 tmp[8];
        *(uint4*)tmp = *(const uint4*)(qkv + gbase + (size_t)key * NQKV + 2048 + dseg * 8);
#pragma unroll
        for (int j = 0; j < 8; j++)
            vt[(dseg * 8 + j) * VT + key] = tmp[j];
    }
    if (t < 64) {
        const int gl = c * CHUNK - 1;
        float kpv = 0.f, vpv = 0.f;
        if (gl >= 0) {
            const size_t go = base + (size_t)gl * NQKV + t;
            kpv = bf2f(qkv[go + 1024]);
            vpv = bf2f(qkv[go + 2048]);
        }
        kp[t] = kpv; vp[t] = vpv;
    }
    __syncthreads();

    // ---- carry scores s0[row] = q_row . k_prev (2 threads per row) ----
    {
        const int row = t >> 1, half = t & 1;
        const u16* qrow = &qk[row * QS + half * 32];
        float s = 0.f;
#pragma unroll
        for (int d = 0; d < 32; d++) s += bf2f(qrow[d]) * kp[half * 32 + d];
        s += __shfl_xor(s, 1, 64);
        if (half == 0) s0f[row] = s;
    }
    __syncthreads();

    // ---- S-MFMA: wave w computes rows R0..R0+32 x all 128 keys ----
    floatx4 accs[2][8];
#pragma unroll
    for (int rt = 0; rt < 2; rt++)
#pragma unroll
        for (int ct = 0; ct < 8; ct++)
            accs[rt][ct] = floatx4{0.f, 0.f, 0.f, 0.f};

#pragma unroll
    for (int k0 = 0; k0 < 2; k0++) {
        bf16x8 af0 = *(const bf16x8*)&qk[(R0 + col16) * QS + k0 * 32 + quad * 8];
        bf16x8 af1 = *(const bf16x8*)&qk[(R0 + 16 + col16) * QS + k0 * 32 + quad * 8];
#pragma unroll
        for (int ct = 0; ct < 8; ct++) {
            bf16x8 bfr = *(const bf16x8*)&qk[KS_OFF + (ct * 16 + col16) * QS + k0 * 32 + quad * 8];
            accs[0][ct] = __builtin_amdgcn_mfma_f32_16x16x32_bf16(af0, bfr, accs[0][ct], 0, 0, 0);
            accs[1][ct] = __builtin_amdgcn_mfma_f32_16x16x32_bf16(af1, bfr, accs[1][ct], 0, 0, 0);
        }
    }
    __syncthreads();   // all waves done reading qk before Ps overlay

    // ---- softmax per row in-register; write unnormalized P (bf16) ----
    const float dval = load_decay(dec, h);
    const float logd = __logf(dval);
    float p0v[2][4], invv[2][4];
#pragma unroll
    for (int rt = 0; rt < 2; rt++) {
#pragma unroll
        for (int r = 0; r < 4; r++) {
            const int row = R0 + rt * 16 + quad * 4 + r;
            const float dp = __expf((float)row * logd) * 0.125f;
            const float s0p = s0f[row] * dp;
            float vals[8];
            float vmax = s0p;
#pragma unroll
            for (int ct = 0; ct < 8; ct++) {
                vals[ct] = accs[rt][ct][r] * dp;
                vmax = fmaxf(vmax, vals[ct]);
            }
#pragma unroll
            for (int off = 1; off < 16; off <<= 1)
                vmax = fmaxf(vmax, __shfl_xor(vmax, off, 64));
            float lsum = 0.f;
#pragma unroll
            for (int ct = 0; ct < 8; ct++) {
                const float e = __expf(vals[ct] - vmax);
                lsum += e;
                Ps[row * PS + ct * 16 + col16] = f2bf(e);
            }
#pragma unroll
            for (int off = 1; off < 16; off <<= 1)
                lsum += __shfl_xor(lsum, off, 64);
            const float p0 = __expf(s0p - vmax);
            p0v[rt][r] = p0;
            invv[rt][r] = 1.0f / (lsum + p0);
        }
    }
    // no barrier needed: wave w only re-reads its own rows of Ps

    // ---- PV-MFMA: O[R0..R0+32][0..64] ----
    floatx4 acco[2][4];
#pragma unroll
    for (int rt = 0; rt < 2; rt++)
#pragma unroll
        for (int nt = 0; nt < 4; nt++)
            acco[rt][nt] = floatx4{0.f, 0.f, 0.f, 0.f};

#pragma unroll
    for (int k0 = 0; k0 < 4; k0++) {
        bf16x8 af0 = *(const bf16x8*)&Ps[(R0 + col16) * PS + k0 * 32 + quad * 8];
        bf16x8 af1 = *(const bf16x8*)&Ps[(R0 + 16 + col16) * PS + k0 * 32 + quad * 8];
#pragma unroll
        for (int nt = 0; nt < 4; nt++) {
            bf16x8 bfr = *(const bf16x8*)&vt[(nt * 16 + col16) * VT + k0 * 32 + quad * 8];
            acco[0][nt] = __builtin_amdgcn_mfma_f32_16x16x32_bf16(af0, bfr, acco[0][nt], 0, 0, 0);
            acco[1][nt] = __builtin_amdgcn_mfma_f32_16x16x32_bf16(af1, bfr, acco[1][nt], 0, 0, 0);
        }
    }

    // ---- epilogue: add carry rank-1 term, normalize, store bf16 ----
#pragma unroll
    for (int nt = 0; nt < 4; nt++) {
        const int gcol = nt * 16 + col16;
        const float vpc = vp[gcol];
#pragma unroll
        for (int rt = 0; rt < 2; rt++) {
#pragma unroll
            for (int r = 0; r < 4; r++) {
                const int row = R0 + rt * 16 + quad * 4 + r;
                const float val = (acco[rt][nt][r] + p0v[rt][r] * vpc) * invv[rt][r];
                att[obase + (size_t)row * D_MODEL + gcol] = f2bf(val);
            }
        }
    }
}

// ---------------------------- launcher -------------------------------------
extern "C" void kernel_launch(void* const* d_in, const int* in_sizes, int n_in,
                              void* d_out, int out_size, void* d_ws, size_t ws_size,
                              hipStream_t stream) {
    const void* x   = d_in[0];
    const void* Wq  = d_in[1];
    const void* bq  = d_in[2];
    const void* Wk  = d_in[3];
    const void* bk  = d_in[4];
    const void* Wv  = d_in[5];
    const void* bv  = d_in[6];
    const void* Wo  = d_in[7];
    const void* bo  = d_in[8];
    const void* dec = d_in[9];
    float* out = (float*)d_out;               // reference output dtype: fp32

    char* ws = (char*)d_ws;
    const size_t mat = (size_t)M_ROWS * D_MODEL * sizeof(u16);   // 33.5 MB
    const size_t wsz = (size_t)D_MODEL * D_MODEL * sizeof(u16);  // 2 MB
    u16* xb   = (u16*)(ws);                   // canonical bf16 x; later att
    u16* qkv  = (u16*)(ws + mat);             // fused [16384][3072]
    u16* WT   = (u16*)(ws + 4 * mat);         // WqT|WkT|WvT|WoT contiguous
    u16* WoT  = WT + 3 * (size_t)D_MODEL * D_MODEL;
    u16* bias = (u16*)(ws + 4 * mat + 4 * wsz);   // bq|bk|bv|bo bf16
    int* flags = (int*)(ws + 4 * mat + 4 * wsz + 8192);

    dim3 tb(256);
    detect_dtypes<<<1, 64, 0, stream>>>(x, Wq, flags);
    convert_x<<<8192, tb, 0, stream>>>(x, flags, xb);
    transpose4<<<dim3(32, 32, 4), tb, 0, stream>>>(
        Wq, Wk, Wv, Wo, flags,
        WT, WT + wsz / 2, WT + wsz, WoT);
    concat_bias<<<16, tb, 0, stream>>>(bq, bk, bv, bo, flags, bias);
    // fused QKV: N=3072 -> 64 row-groups x 12 col-tiles = 768 blocks
    gemm_256<u16><<<dim3(64 * 12), dim3(512), 131072, stream>>>(
        xb, WT, bias, qkv, NQKV);
    retention_mfma<<<dim3(N_CHUNKS, BATCH, N_HEADS), tb, 0, stream>>>(qkv, dec, xb);
    // output projection: N=1024 -> 64 x 4 = 256 blocks
    gemm_256<float><<<dim3(64 * 4), dim3(512), 131072, stream>>>(
        xb, WoT, bias + 3072, out, D_MODEL);
}

// Round 5
// 335.469 us; speedup vs baseline: 1.0700x; 1.0700x over previous
//
#include <hip/hip_runtime.h>

typedef unsigned short u16;
typedef unsigned int   u32;
typedef unsigned long long u64;

typedef __attribute__((ext_vector_type(8))) __bf16 bf16x8;
typedef __attribute__((ext_vector_type(4))) float  floatx4;
typedef __attribute__((ext_vector_type(16))) float floatx16;

#define D_MODEL 1024
#define L_SEQ   4096
#define BATCH   4
#define N_HEADS 16
#define D_HEAD  64
#define CHUNK   128
#define N_CHUNKS 32
#define M_ROWS  (BATCH * L_SEQ)   // 16384
#define NQKV    3072              // fused q|k|v output width

// ---------- bf16 helpers ----------
__device__ __forceinline__ float bf2f(u16 u) {
    union { u32 i; float f; } x; x.i = ((u32)u) << 16; return x.f;
}
__device__ __forceinline__ u16 f2bf(float f) {
    union { u32 i; float fl; } x; x.fl = f;
    u32 i = x.i;
    u32 r = (i + 0x7FFFu + ((i >> 16) & 1u)) >> 16;
    return (u16)r;
}

__device__ __forceinline__ float load_decay(const void* dec, int h) {
    const u16* d16 = (const u16*)dec;
    const float as_bf = bf2f(d16[0]);
    if (as_bf > 1e-6f && as_bf <= 1.0001f) return bf2f(d16[h]);
    return ((const float*)dec)[h];
}

// direct global->LDS 16B async copy. HW semantics: per-lane global addr;
// LDS dest = wave-uniform base + lane*16 (m97/m104).
__device__ __forceinline__ void gload_lds16(const u16* g, u16* l) {
    __builtin_amdgcn_global_load_lds(
        (const __attribute__((address_space(1))) u32*)g,
        (__attribute__((address_space(3))) u32*)l, 16, 0, 0);
}

// ---------- dtype detection: flags[0]=x is fp32, flags[1]=W is fp32 --------
__global__ void detect_dtypes(const void* __restrict__ x,
                              const void* __restrict__ w,
                              int* __restrict__ flags) {
    const int lane = threadIdx.x;                 // 64 threads
    const u16* x16 = (const u16*)x;
    const u16* w16 = (const u16*)w;
    const float vx = fabsf(bf2f(x16[lane]));
    const float vw = fabsf(bf2f(w16[lane]));
    const bool ox = (vx != 0.0f) && (vx > 1e4f || vx < 1e-4f);
    const bool ow = (vw != 0.0f) && (vw > 1e4f || vw < 1e-4f);
    const u64 bx = __ballot(ox);
    const u64 bw = __ballot(ow);
    if (lane == 0) {
        flags[0] = (__popcll(bx) >= 8) ? 1 : 0;
        flags[1] = (__popcll(bw) >= 8) ? 1 : 0;
    }
}

// ---------- x -> canonical bf16 buffer ----------
__global__ __launch_bounds__(256)
void convert_x(const void* __restrict__ x, const int* __restrict__ flags,
               u16* __restrict__ xb) {
    const int mode = flags[0];
    const size_t i0 = ((size_t)blockIdx.x * 256 + threadIdx.x) * 8;
    if (mode) {
        const float* xf = (const float*)x;
        u16 tmp[8];
#pragma unroll
        for (int j = 0; j < 8; j++) tmp[j] = f2bf(xf[i0 + j]);
        *(uint4*)(xb + i0) = *(const uint4*)tmp;
    } else {
        *(uint4*)(xb + i0) = *(const uint4*)((const u16*)x + i0);
    }
}

// ---------- weight transpose: T[n][k] = bf16(W[k][n]), dual dtype ----------
__global__ __launch_bounds__(256)
void transpose4(const void* __restrict__ W0, const void* __restrict__ W1,
                const void* __restrict__ W2, const void* __restrict__ W3,
                const int* __restrict__ flags,
                u16* __restrict__ T0, u16* __restrict__ T1,
                u16* __restrict__ T2, u16* __restrict__ T3) {
    __shared__ u16 tile[32][33];
    const int mode = flags[1];
    const void* src; u16* dst;
    switch (blockIdx.z) {
        case 0: src = W0; dst = T0; break;
        case 1: src = W1; dst = T1; break;
        case 2: src = W2; dst = T2; break;
        default: src = W3; dst = T3; break;
    }
    const int tx = threadIdx.x & 31, ty = threadIdx.x >> 5;  // ty in 0..7
    const int x0 = blockIdx.x * 32, y0 = blockIdx.y * 32;
#pragma unroll
    for (int i = 0; i < 32; i += 8) {
        const size_t idx = (size_t)(y0 + ty + i) * D_MODEL + x0 + tx;
        tile[ty + i][tx] = mode ? f2bf(((const float*)src)[idx])
                                : ((const u16*)src)[idx];
    }
    __syncthreads();
#pragma unroll
    for (int i = 0; i < 32; i += 8)
        dst[(size_t)(x0 + ty + i) * D_MODEL + y0 + tx] = tile[tx][ty + i];
}

// ---------- bias concat: dst[0..4096) = bf16(bq|bk|bv|bo), dual dtype ------
__global__ __launch_bounds__(256)
void concat_bias(const void* __restrict__ bq, const void* __restrict__ bk,
                 const void* __restrict__ bv, const void* __restrict__ bo,
                 const int* __restrict__ flags, u16* __restrict__ dst) {
    const int i = blockIdx.x * 256 + threadIdx.x;  // 0..4095
    const int mode = flags[1];
    const int which = i >> 10, idx = i & 1023;
    const void* src = (which == 0) ? bq : (which == 1) ? bk
                      : (which == 2) ? bv : bo;
    dst[i] = mode ? f2bf(((const float*)src)[idx]) : ((const u16*)src)[idx];
}

// ---------- 256x256 GEMM (R3-exact revert: best measured, 117 us QKV) ------
// C = A[16384,1024] . Bt[N,1024]^T + bias.
// 512 threads = 8 waves (2M x 4N), BK=64, 2 LDS buffers (128 KiB dynamic).
// 4 phases / K-tile, Gray order, one barrier per phase; tile-end counted
// vmcnt. 32x32x16 MFMA. L2-aware block decode: XCD (bid&7) owns 8 fixed
// A-panels (4 MB = its L2) reused across all n-tiles and rounds.
template <typename OutT>
__global__ __launch_bounds__(512, 2)
void gemm_256(const u16* __restrict__ A, const u16* __restrict__ Bt,
              const u16* __restrict__ bias, OutT* __restrict__ C, int N) {
    extern __shared__ u16 lds[];           // 131072 B: buf0 A|B, buf1 A|B
    constexpr int K  = 1024;
    constexpr int NT = K / 64;             // 16 K-tiles

    const int t = threadIdx.x;
    const int lane = t & 63, w = t >> 6;
    const int l31 = lane & 31, hi = lane >> 5;
    const int wm = w >> 2, wn = w & 3;     // wave grid 2M x 4N

    const int bid = blockIdx.x;
    const int m0 = (((bid & 7) << 3) + ((bid >> 3) & 7)) * 256;
    const int n0 = (bid >> 6) * 256;

    const int rl = lane >> 3;              // row within the wave's 8 rows
    const int sseg = (lane & 7) ^ rl;      // pre-swizzled source segment

    auto STAGE_A = [&](int kt, int half) {
        u16* l0 = lds + (kt & 1) * 32768 + (half * 128 + w * 8) * 64;
        const u16* g0 = A + (size_t)(m0 + half * 128 + w * 8 + rl) * K
                          + kt * 64 + sseg * 8;
        gload_lds16(g0, l0);
        gload_lds16(g0 + (size_t)64 * K, l0 + 64 * 64);
    };
    auto STAGE_B = [&](int kt, int half) {
        u16* l0 = lds + (kt & 1) * 32768 + 16384 + (half * 128 + w * 8) * 64;
        const u16* g0 = Bt + (size_t)(n0 + half * 128 + w * 8 + rl) * K
                           + kt * 64 + sseg * 8;
        gload_lds16(g0, l0);
        gload_lds16(g0 + (size_t)64 * K, l0 + 64 * 64);
    };

    bf16x8 af[2][4], bfr[4];
    floatx16 acc[2][2][2];                 // [mh][nh][row-tile i]
#pragma unroll
    for (int a = 0; a < 2; a++)
#pragma unroll
        for (int b = 0; b < 2; b++)
#pragma unroll
            for (int i = 0; i < 2; i++)
#pragma unroll
                for (int r = 0; r < 16; r++)
                    acc[a][b][i][r] = 0.f;

    auto LDA = [&](int cur, int mh) {
        const u16* tb = lds + cur * 32768;
#pragma unroll
        for (int i = 0; i < 2; i++) {
            const int row = mh * 128 + wm * 64 + i * 32 + l31;
#pragma unroll
            for (int ks = 0; ks < 4; ks++) {
                const int seg = (ks * 2 + hi) ^ (row & 7);
                af[i][ks] = *(const bf16x8*)(tb + row * 64 + seg * 8);
            }
        }
    };
    auto LDB = [&](int cur, int nh) {
        const u16* tb = lds + cur * 32768 + 16384;
        const int row = nh * 128 + wn * 32 + l31;
#pragma unroll
        for (int ks = 0; ks < 4; ks++) {
            const int seg = (ks * 2 + hi) ^ (row & 7);
            bfr[ks] = *(const bf16x8*)(tb + row * 64 + seg * 8);
        }
    };
    auto MMQ = [&](floatx16 (&aq)[2]) {
        __builtin_amdgcn_s_setprio(1);
#pragma unroll
        for (int i = 0; i < 2; i++)
#pragma unroll
            for (int ks = 0; ks < 4; ks++)
                aq[i] = __builtin_amdgcn_mfma_f32_32x32x16_bf16(
                    af[i][ks], bfr[ks], aq[i], 0, 0, 0);
        __builtin_amdgcn_s_setprio(0);
    };

    // ---- prologue: kt0 fully + kt1's (A0,B1) in flight ----
    STAGE_A(0, 0); STAGE_B(0, 0); STAGE_A(0, 1); STAGE_B(0, 1);
    STAGE_A(1, 0); STAGE_B(1, 1);
    asm volatile("s_waitcnt vmcnt(4)" ::: "memory");  // kt0 landed
    __builtin_amdgcn_s_barrier();

    for (int kt = 0; kt < NT; ++kt) {
        const int cur = kt & 1;
        // phase 1: quadrant (0,0)
        LDA(cur, 0); LDB(cur, 0);
        if (kt + 1 < NT) STAGE_A(kt + 1, 1);
        __builtin_amdgcn_s_barrier();
        MMQ(acc[0][0]);
        // phase 2: (0,1) — A frags reused
        LDB(cur, 1);
        if (kt + 1 < NT) STAGE_B(kt + 1, 0);
        __builtin_amdgcn_s_barrier();
        MMQ(acc[0][1]);
        // phase 3: (1,1) — B frags reused
        LDA(cur, 1);
        if (kt + 2 < NT) STAGE_A(kt + 2, 0);
        __builtin_amdgcn_s_barrier();
        MMQ(acc[1][1]);
        // phase 4: (1,0) — A frags reused
        LDB(cur, 0);
        if (kt + 2 < NT) STAGE_B(kt + 2, 1);
        __builtin_amdgcn_s_barrier();
        MMQ(acc[1][0]);
        // counted wait: kt+1's 4 halves landed; kt+2's 2 stay in flight
        if (kt + 2 < NT) asm volatile("s_waitcnt vmcnt(4)" ::: "memory");
        else             asm volatile("s_waitcnt vmcnt(0)" ::: "memory");
        __builtin_amdgcn_s_barrier();
    }

    // ---- epilogue. 32x32 C/D layout: col=lane&31,
    //      row = (reg&3) + 8*(reg>>2) + 4*(lane>>5)  [m74/m101] ----
    if constexpr (sizeof(OutT) == 2) {
        u16* sm = lds;
#pragma unroll
        for (int mh = 0; mh < 2; mh++) {
            __syncthreads();
#pragma unroll
            for (int nh = 0; nh < 2; nh++) {
                const int lcol = nh * 128 + wn * 32 + l31;
                const float bsf = bf2f(bias[n0 + lcol]);
#pragma unroll
                for (int i = 0; i < 2; i++)
#pragma unroll
                    for (int r = 0; r < 16; r++) {
                        const int srow = wm * 64 + i * 32 +
                                         (r & 3) + 8 * (r >> 2) + 4 * hi;
                        sm[srow * 264 + lcol] = f2bf(acc[mh][nh][i][r] + bsf);
                    }
            }
            __syncthreads();
#pragma unroll
            for (int it = 0; it < 8; it++) {
                const int lin = it * 512 + t;
                const int row = lin >> 5, seg = lin & 31;
                *(uint4*)&C[(size_t)(m0 + mh * 128 + row) * N + n0 + seg * 8] =
                    *(const uint4*)&sm[row * 264 + seg * 8];
            }
        }
    } else {
#pragma unroll
        for (int mh = 0; mh < 2; mh++)
#pragma unroll
            for (int nh = 0; nh < 2; nh++) {
                const int gcol = n0 + nh * 128 + wn * 32 + l31;
                const float bsf = bf2f(bias[gcol]);
#pragma unroll
                for (int i = 0; i < 2; i++)
#pragma unroll
                    for (int r = 0; r < 16; r++) {
                        const int gr = m0 + mh * 128 + wm * 64 + i * 32 +
                                       (r & 3) + 8 * (r >> 2) + 4 * hi;
                        C[(size_t)gr * N + gcol] = acc[mh][nh][i][r] + bsf;
                    }
            }
    }
}

// ---------- retention via MFMA: one block per (chunk, b, h) tile -----------
// Reads fused qkv [16384][3072] (q|k|v); writes att [16384][1024].
// R5: O-tile repacked through LDS (overlaying qk, barrier-protected) so
// att is written as 16-B uint4 rows instead of 32 scalar 2-B stores/lane.
#define QS 72
#define PS 136
#define VT 136
#define OS 72
#define KS_OFF (128 * QS)

__global__ __launch_bounds__(256)
void retention_mfma(const u16* __restrict__ qkv, const void* __restrict__ dec,
                    u16* __restrict__ att) {
    __shared__ u16 qk[2 * 128 * QS];   // Qs | Ks ; overlaid by Ps, then Osm
    __shared__ u16 vt[64 * VT];        // V^T: [d][key]
    __shared__ float kp[64], vp[64], s0f[128];
    u16* Ps = qk;
    u16* Osm = qk;                     // 128 x OS (18.4 KB) after PV

    const int c = blockIdx.x, b = blockIdx.y, h = blockIdx.z;
    const int t = threadIdx.x;
    const int lane = t & 63, w = t >> 6;
    const int col16 = lane & 15, quad = lane >> 4;
    const int R0 = w * 32;
    const size_t base  = ((size_t)b * L_SEQ) * NQKV + h * D_HEAD;
    const size_t gbase = base + (size_t)(c * CHUNK) * NQKV;
    const size_t obase = (((size_t)b * L_SEQ) + c * CHUNK) * D_MODEL + h * D_HEAD;

    // ---- stage Q, K (row-major) and V (transposed) ----
#pragma unroll
    for (int it = 0; it < 4; it++) {
        const int i = it * 256 + t;
        const int row = i >> 3, seg = i & 7;
        const size_t go = gbase + (size_t)row * NQKV + seg * 8;
        *(uint4*)&qk[row * QS + seg * 8]          = *(const uint4*)(qkv + go);
        *(uint4*)&qk[KS_OFF + row * QS + seg * 8] = *(const uint4*)(qkv + go + 1024);
    }
#pragma unroll
    for (int it = 0; it < 4; it++) {
        const int i = it * 256 + t;
        const int key = i & 127, dseg = i >> 7;
        u16 tmp[8];
        *(uint4*)tmp = *(const uint4*)(qkv + gbase + (size_t)key * NQKV + 2048 + dseg * 8);
#pragma unroll
        for (int j = 0; j < 8; j++)
            vt[(dseg * 8 + j) * VT + key] = tmp[j];
    }
    if (t < 64) {
        const int gl = c * CHUNK - 1;
        float kpv = 0.f, vpv = 0.f;
        if (gl >= 0) {
            const size_t go = base + (size_t)gl * NQKV + t;
            kpv = bf2f(qkv[go + 1024]);
            vpv = bf2f(qkv[go + 2048]);
        }
        kp[t] = kpv; vp[t] = vpv;
    }
    __syncthreads();

    // ---- carry scores s0[row] = q_row . k_prev (2 threads per row) ----
    {
        const int row = t >> 1, half = t & 1;
        const u16* qrow = &qk[row * QS + half * 32];
        float s = 0.f;
#pragma unroll
        for (int d = 0; d < 32; d++) s += bf2f(qrow[d]) * kp[half * 32 + d];
        s += __shfl_xor(s, 1, 64);
        if (half == 0) s0f[row] = s;
    }
    __syncthreads();

    // ---- S-MFMA: wave w computes rows R0..R0+32 x all 128 keys ----
    floatx4 accs[2][8];
#pragma unroll
    for (int rt = 0; rt < 2; rt++)
#pragma unroll
        for (int ct = 0; ct < 8; ct++)
            accs[rt][ct] = floatx4{0.f, 0.f, 0.f, 0.f};

#pragma unroll
    for (int k0 = 0; k0 < 2; k0++) {
        bf16x8 af0 = *(const bf16x8*)&qk[(R0 + col16) * QS + k0 * 32 + quad * 8];
        bf16x8 af1 = *(const bf16x8*)&qk[(R0 + 16 + col16) * QS + k0 * 32 + quad * 8];
#pragma unroll
        for (int ct = 0; ct < 8; ct++) {
            bf16x8 bfr = *(const bf16x8*)&qk[KS_OFF + (ct * 16 + col16) * QS + k0 * 32 + quad * 8];
            accs[0][ct] = __builtin_amdgcn_mfma_f32_16x16x32_bf16(af0, bfr, accs[0][ct], 0, 0, 0);
            accs[1][ct] = __builtin_amdgcn_mfma_f32_16x16x32_bf16(af1, bfr, accs[1][ct], 0, 0, 0);
        }
    }
    __syncthreads();   // all waves done reading qk before Ps overlay

    // ---- softmax per row in-register; write unnormalized P (bf16) ----
    const float dval = load_decay(dec, h);
    const float logd = __logf(dval);
    float p0v[2][4], invv[2][4];
#pragma unroll
    for (int rt = 0; rt < 2; rt++) {
#pragma unroll
        for (int r = 0; r < 4; r++) {
            const int row = R0 + rt * 16 + quad * 4 + r;
            const float dp = __expf((float)row * logd) * 0.125f;
            const float s0p = s0f[row] * dp;
            float vals[8];
            float vmax = s0p;
#pragma unroll
            for (int ct = 0; ct < 8; ct++) {
                vals[ct] = accs[rt][ct][r] * dp;
                vmax = fmaxf(vmax, vals[ct]);
            }
#pragma unroll
            for (int off = 1; off < 16; off <<= 1)
                vmax = fmaxf(vmax, __shfl_xor(vmax, off, 64));
            float lsum = 0.f;
#pragma unroll
            for (int ct = 0; ct < 8; ct++) {
                const float e = __expf(vals[ct] - vmax);
                lsum += e;
                Ps[row * PS + ct * 16 + col16] = f2bf(e);
            }
#pragma unroll
            for (int off = 1; off < 16; off <<= 1)
                lsum += __shfl_xor(lsum, off, 64);
            const float p0 = __expf(s0p - vmax);
            p0v[rt][r] = p0;
            invv[rt][r] = 1.0f / (lsum + p0);
        }
    }
    // no barrier needed: wave w only re-reads its own rows of Ps

    // ---- PV-MFMA: O[R0..R0+32][0..64] ----
    floatx4 acco[2][4];
#pragma unroll
    for (int rt = 0; rt < 2; rt++)
#pragma unroll
        for (int nt = 0; nt < 4; nt++)
            acco[rt][nt] = floatx4{0.f, 0.f, 0.f, 0.f};

#pragma unroll
    for (int k0 = 0; k0 < 4; k0++) {
        bf16x8 af0 = *(const bf16x8*)&Ps[(R0 + col16) * PS + k0 * 32 + quad * 8];
        bf16x8 af1 = *(const bf16x8*)&Ps[(R0 + 16 + col16) * PS + k0 * 32 + quad * 8];
#pragma unroll
        for (int nt = 0; nt < 4; nt++) {
            bf16x8 bfr = *(const bf16x8*)&vt[(nt * 16 + col16) * VT + k0 * 32 + quad * 8];
            acco[0][nt] = __builtin_amdgcn_mfma_f32_16x16x32_bf16(af0, bfr, acco[0][nt], 0, 0, 0);
            acco[1][nt] = __builtin_amdgcn_mfma_f32_16x16x32_bf16(af1, bfr, acco[1][nt], 0, 0, 0);
        }
    }

    // ---- epilogue: carry rank-1 term + normalize -> LDS repack ----
    __syncthreads();   // ALL waves done reading Ps (Osm overlays it)
#pragma unroll
    for (int nt = 0; nt < 4; nt++) {
        const int gcol = nt * 16 + col16;
        const float vpc = vp[gcol];
#pragma unroll
        for (int rt = 0; rt < 2; rt++) {
#pragma unroll
            for (int r = 0; r < 4; r++) {
                const int row = R0 + rt * 16 + quad * 4 + r;
                const float val = (acco[rt][nt][r] + p0v[rt][r] * vpc) * invv[rt][r];
                Osm[row * OS + gcol] = f2bf(val);
            }
        }
    }
    __syncthreads();
    // ---- coalesced store: 128 rows x 8 uint4-segments, 4 per thread ----
#pragma unroll
    for (int it = 0; it < 4; it++) {
        const int lin = it * 256 + t;
        const int row = lin >> 3, seg = lin & 7;
        *(uint4*)&att[obase + (size_t)row * D_MODEL + seg * 8] =
            *(const uint4*)&Osm[row * OS + seg * 8];
    }
}

// ---------------------------- launcher -------------------------------------
extern "C" void kernel_launch(void* const* d_in, const int* in_sizes, int n_in,
                              void* d_out, int out_size, void* d_ws, size_t ws_size,
                              hipStream_t stream) {
    const void* x   = d_in[0];
    const void* Wq  = d_in[1];
    const void* bq  = d_in[2];
    const void* Wk  = d_in[3];
    const void* bk  = d_in[4];
    const void* Wv  = d_in[5];
    const void* bv  = d_in[6];
    const void* Wo  = d_in[7];
    const void* bo  = d_in[8];
    const void* dec = d_in[9];
    float* out = (float*)d_out;               // reference output dtype: fp32

    char* ws = (char*)d_ws;
    const size_t mat = (size_t)M_ROWS * D_MODEL * sizeof(u16);   // 33.5 MB
    const size_t wsz = (size_t)D_MODEL * D_MODEL * sizeof(u16);  // 2 MB
    u16* xb   = (u16*)(ws);                   // canonical bf16 x; later att
    u16* qkv  = (u16*)(ws + mat);             // fused [16384][3072]
    u16* WT   = (u16*)(ws + 4 * mat);         // WqT|WkT|WvT|WoT contiguous
    u16* WoT  = WT + 3 * (size_t)D_MODEL * D_MODEL;
    u16* bias = (u16*)(ws + 4 * mat + 4 * wsz);   // bq|bk|bv|bo bf16
    int* flags = (int*)(ws + 4 * mat + 4 * wsz + 8192);

    dim3 tb(256);
    detect_dtypes<<<1, 64, 0, stream>>>(x, Wq, flags);
    convert_x<<<8192, tb, 0, stream>>>(x, flags, xb);
    transpose4<<<dim3(32, 32, 4), tb, 0, stream>>>(
        Wq, Wk, Wv, Wo, flags,
        WT, WT + wsz / 2, WT + wsz, WoT);
    concat_bias<<<16, tb, 0, stream>>>(bq, bk, bv, bo, flags, bias);
    // fused QKV: N=3072 -> 64 row-groups x 12 col-tiles = 768 blocks
    gemm_256<u16><<<dim3(64 * 12), dim3(512), 131072, stream>>>(
        xb, WT, bias, qkv, NQKV);
    retention_mfma<<<dim3(N_CHUNKS, BATCH, N_HEADS), tb, 0, stream>>>(qkv, dec, xb);
    // output projection: N=1024 -> 64 x 4 = 256 blocks
    gemm_256<float><<<dim3(64 * 4), dim3(512), 131072, stream>>>(
        xb, WoT, bias + 3072, out, D_MODEL);
}

// Round 6
// 333.189 us; speedup vs baseline: 1.0773x; 1.0068x over previous
//
#include <hip/hip_runtime.h>

typedef unsigned short u16;
typedef unsigned int   u32;
typedef unsigned long long u64;

typedef __attribute__((ext_vector_type(8))) __bf16 bf16x8;
typedef __attribute__((ext_vector_type(4))) float  floatx4;
typedef __attribute__((ext_vector_type(16))) float floatx16;

#define D_MODEL 1024
#define L_SEQ   4096
#define BATCH   4
#define N_HEADS 16
#define D_HEAD  64
#define CHUNK   128
#define N_CHUNKS 32
#define M_ROWS  (BATCH * L_SEQ)   // 16384
#define NQKV    3072              // fused q|k|v output width

// ---------- bf16 helpers ----------
__device__ __forceinline__ float bf2f(u16 u) {
    union { u32 i; float f; } x; x.i = ((u32)u) << 16; return x.f;
}
__device__ __forceinline__ u16 f2bf(float f) {
    union { u32 i; float fl; } x; x.fl = f;
    u32 i = x.i;
    u32 r = (i + 0x7FFFu + ((i >> 16) & 1u)) >> 16;
    return (u16)r;
}
__device__ __forceinline__ u32 pk2(float a, float b) {
    return (u32)f2bf(a) | ((u32)f2bf(b) << 16);
}

__device__ __forceinline__ float load_decay(const void* dec, int h) {
    const u16* d16 = (const u16*)dec;
    const float as_bf = bf2f(d16[0]);
    if (as_bf > 1e-6f && as_bf <= 1.0001f) return bf2f(d16[h]);
    return ((const float*)dec)[h];
}

// direct global->LDS 16B async copy. HW semantics: per-lane global addr;
// LDS dest = wave-uniform base + lane*16 (m97/m104).
__device__ __forceinline__ void gload_lds16(const u16* g, u16* l) {
    __builtin_amdgcn_global_load_lds(
        (const __attribute__((address_space(1))) u32*)g,
        (__attribute__((address_space(3))) u32*)l, 16, 0, 0);
}

// ---------- dtype detection: flags[0]=x is fp32, flags[1]=W is fp32 --------
__global__ void detect_dtypes(const void* __restrict__ x,
                              const void* __restrict__ w,
                              int* __restrict__ flags) {
    const int lane = threadIdx.x;                 // 64 threads
    const u16* x16 = (const u16*)x;
    const u16* w16 = (const u16*)w;
    const float vx = fabsf(bf2f(x16[lane]));
    const float vw = fabsf(bf2f(w16[lane]));
    const bool ox = (vx != 0.0f) && (vx > 1e4f || vx < 1e-4f);
    const bool ow = (vw != 0.0f) && (vw > 1e4f || vw < 1e-4f);
    const u64 bx = __ballot(ox);
    const u64 bw = __ballot(ow);
    if (lane == 0) {
        flags[0] = (__popcll(bx) >= 8) ? 1 : 0;
        flags[1] = (__popcll(bw) >= 8) ? 1 : 0;
    }
}

// ---------- x -> canonical bf16 buffer ----------
__global__ __launch_bounds__(256)
void convert_x(const void* __restrict__ x, const int* __restrict__ flags,
               u16* __restrict__ xb) {
    const int mode = flags[0];
    const size_t i0 = ((size_t)blockIdx.x * 256 + threadIdx.x) * 8;
    if (mode) {
        const float* xf = (const float*)x;
        u16 tmp[8];
#pragma unroll
        for (int j = 0; j < 8; j++) tmp[j] = f2bf(xf[i0 + j]);
        *(uint4*)(xb + i0) = *(const uint4*)tmp;
    } else {
        *(uint4*)(xb + i0) = *(const uint4*)((const u16*)x + i0);
    }
}

// ---------- weight transpose: T[n][k] = bf16(W[k][n]), dual dtype ----------
__global__ __launch_bounds__(256)
void transpose4(const void* __restrict__ W0, const void* __restrict__ W1,
                const void* __restrict__ W2, const void* __restrict__ W3,
                const int* __restrict__ flags,
                u16* __restrict__ T0, u16* __restrict__ T1,
                u16* __restrict__ T2, u16* __restrict__ T3) {
    __shared__ u16 tile[32][33];
    const int mode = flags[1];
    const void* src; u16* dst;
    switch (blockIdx.z) {
        case 0: src = W0; dst = T0; break;
        case 1: src = W1; dst = T1; break;
        case 2: src = W2; dst = T2; break;
        default: src = W3; dst = T3; break;
    }
    const int tx = threadIdx.x & 31, ty = threadIdx.x >> 5;  // ty in 0..7
    const int x0 = blockIdx.x * 32, y0 = blockIdx.y * 32;
#pragma unroll
    for (int i = 0; i < 32; i += 8) {
        const size_t idx = (size_t)(y0 + ty + i) * D_MODEL + x0 + tx;
        tile[ty + i][tx] = mode ? f2bf(((const float*)src)[idx])
                                : ((const u16*)src)[idx];
    }
    __syncthreads();
#pragma unroll
    for (int i = 0; i < 32; i += 8)
        dst[(size_t)(x0 + ty + i) * D_MODEL + y0 + tx] = tile[tx][ty + i];
}

// ---------- bias concat: dst[0..4096) = bf16(bq|bk|bv|bo), dual dtype ------
__global__ __launch_bounds__(256)
void concat_bias(const void* __restrict__ bq, const void* __restrict__ bk,
                 const void* __restrict__ bv, const void* __restrict__ bo,
                 const int* __restrict__ flags, u16* __restrict__ dst) {
    const int i = blockIdx.x * 256 + threadIdx.x;  // 0..4095
    const int mode = flags[1];
    const int which = i >> 10, idx = i & 1023;
    const void* src = (which == 0) ? bq : (which == 1) ? bk
                      : (which == 2) ? bv : bo;
    dst[i] = mode ? f2bf(((const float*)src)[idx]) : ((const u16*)src)[idx];
}

// ---------- 256x256 GEMM (R5-exact: best measured, ~114 us QKV) ------------
template <typename OutT>
__global__ __launch_bounds__(512, 2)
void gemm_256(const u16* __restrict__ A, const u16* __restrict__ Bt,
              const u16* __restrict__ bias, OutT* __restrict__ C, int N) {
    extern __shared__ u16 lds[];           // 131072 B: buf0 A|B, buf1 A|B
    constexpr int K  = 1024;
    constexpr int NT = K / 64;             // 16 K-tiles

    const int t = threadIdx.x;
    const int lane = t & 63, w = t >> 6;
    const int l31 = lane & 31, hi = lane >> 5;
    const int wm = w >> 2, wn = w & 3;     // wave grid 2M x 4N

    const int bid = blockIdx.x;
    const int m0 = (((bid & 7) << 3) + ((bid >> 3) & 7)) * 256;
    const int n0 = (bid >> 6) * 256;

    const int rl = lane >> 3;              // row within the wave's 8 rows
    const int sseg = (lane & 7) ^ rl;      // pre-swizzled source segment

    auto STAGE_A = [&](int kt, int half) {
        u16* l0 = lds + (kt & 1) * 32768 + (half * 128 + w * 8) * 64;
        const u16* g0 = A + (size_t)(m0 + half * 128 + w * 8 + rl) * K
                          + kt * 64 + sseg * 8;
        gload_lds16(g0, l0);
        gload_lds16(g0 + (size_t)64 * K, l0 + 64 * 64);
    };
    auto STAGE_B = [&](int kt, int half) {
        u16* l0 = lds + (kt & 1) * 32768 + 16384 + (half * 128 + w * 8) * 64;
        const u16* g0 = Bt + (size_t)(n0 + half * 128 + w * 8 + rl) * K
                           + kt * 64 + sseg * 8;
        gload_lds16(g0, l0);
        gload_lds16(g0 + (size_t)64 * K, l0 + 64 * 64);
    };

    bf16x8 af[2][4], bfr[4];
    floatx16 acc[2][2][2];                 // [mh][nh][row-tile i]
#pragma unroll
    for (int a = 0; a < 2; a++)
#pragma unroll
        for (int b = 0; b < 2; b++)
#pragma unroll
            for (int i = 0; i < 2; i++)
#pragma unroll
                for (int r = 0; r < 16; r++)
                    acc[a][b][i][r] = 0.f;

    auto LDA = [&](int cur, int mh) {
        const u16* tb = lds + cur * 32768;
#pragma unroll
        for (int i = 0; i < 2; i++) {
            const int row = mh * 128 + wm * 64 + i * 32 + l31;
#pragma unroll
            for (int ks = 0; ks < 4; ks++) {
                const int seg = (ks * 2 + hi) ^ (row & 7);
                af[i][ks] = *(const bf16x8*)(tb + row * 64 + seg * 8);
            }
        }
    };
    auto LDB = [&](int cur, int nh) {
        const u16* tb = lds + cur * 32768 + 16384;
        const int row = nh * 128 + wn * 32 + l31;
#pragma unroll
        for (int ks = 0; ks < 4; ks++) {
            const int seg = (ks * 2 + hi) ^ (row & 7);
            bfr[ks] = *(const bf16x8*)(tb + row * 64 + seg * 8);
        }
    };
    auto MMQ = [&](floatx16 (&aq)[2]) {
        __builtin_amdgcn_s_setprio(1);
#pragma unroll
        for (int i = 0; i < 2; i++)
#pragma unroll
            for (int ks = 0; ks < 4; ks++)
                aq[i] = __builtin_amdgcn_mfma_f32_32x32x16_bf16(
                    af[i][ks], bfr[ks], aq[i], 0, 0, 0);
        __builtin_amdgcn_s_setprio(0);
    };

    // ---- prologue: kt0 fully + kt1's (A0,B1) in flight ----
    STAGE_A(0, 0); STAGE_B(0, 0); STAGE_A(0, 1); STAGE_B(0, 1);
    STAGE_A(1, 0); STAGE_B(1, 1);
    asm volatile("s_waitcnt vmcnt(4)" ::: "memory");  // kt0 landed
    __builtin_amdgcn_s_barrier();

    for (int kt = 0; kt < NT; ++kt) {
        const int cur = kt & 1;
        // phase 1: quadrant (0,0)
        LDA(cur, 0); LDB(cur, 0);
        if (kt + 1 < NT) STAGE_A(kt + 1, 1);
        __builtin_amdgcn_s_barrier();
        MMQ(acc[0][0]);
        // phase 2: (0,1) — A frags reused
        LDB(cur, 1);
        if (kt + 1 < NT) STAGE_B(kt + 1, 0);
        __builtin_amdgcn_s_barrier();
        MMQ(acc[0][1]);
        // phase 3: (1,1) — B frags reused
        LDA(cur, 1);
        if (kt + 2 < NT) STAGE_A(kt + 2, 0);
        __builtin_amdgcn_s_barrier();
        MMQ(acc[1][1]);
        // phase 4: (1,0) — A frags reused
        LDB(cur, 0);
        if (kt + 2 < NT) STAGE_B(kt + 2, 1);
        __builtin_amdgcn_s_barrier();
        MMQ(acc[1][0]);
        // counted wait: kt+1's 4 halves landed; kt+2's 2 stay in flight
        if (kt + 2 < NT) asm volatile("s_waitcnt vmcnt(4)" ::: "memory");
        else             asm volatile("s_waitcnt vmcnt(0)" ::: "memory");
        __builtin_amdgcn_s_barrier();
    }

    // ---- epilogue. 32x32 C/D layout: col=lane&31,
    //      row = (reg&3) + 8*(reg>>2) + 4*(lane>>5)  [m74/m101] ----
    if constexpr (sizeof(OutT) == 2) {
        u16* sm = lds;
#pragma unroll
        for (int mh = 0; mh < 2; mh++) {
            __syncthreads();
#pragma unroll
            for (int nh = 0; nh < 2; nh++) {
                const int lcol = nh * 128 + wn * 32 + l31;
                const float bsf = bf2f(bias[n0 + lcol]);
#pragma unroll
                for (int i = 0; i < 2; i++)
#pragma unroll
                    for (int r = 0; r < 16; r++) {
                        const int srow = wm * 64 + i * 32 +
                                         (r & 3) + 8 * (r >> 2) + 4 * hi;
                        sm[srow * 264 + lcol] = f2bf(acc[mh][nh][i][r] + bsf);
                    }
            }
            __syncthreads();
#pragma unroll
            for (int it = 0; it < 8; it++) {
                const int lin = it * 512 + t;
                const int row = lin >> 5, seg = lin & 31;
                *(uint4*)&C[(size_t)(m0 + mh * 128 + row) * N + n0 + seg * 8] =
                    *(const uint4*)&sm[row * 264 + seg * 8];
            }
        }
    } else {
#pragma unroll
        for (int mh = 0; mh < 2; mh++)
#pragma unroll
            for (int nh = 0; nh < 2; nh++) {
                const int gcol = n0 + nh * 128 + wn * 32 + l31;
                const float bsf = bf2f(bias[gcol]);
#pragma unroll
                for (int i = 0; i < 2; i++)
#pragma unroll
                    for (int r = 0; r < 16; r++) {
                        const int gr = m0 + mh * 128 + wm * 64 + i * 32 +
                                       (r & 3) + 8 * (r >> 2) + 4 * hi;
                        C[(size_t)gr * N + gcol] = acc[mh][nh][i][r] + bsf;
                    }
            }
    }
}

// ---------- retention, swapped-operand form ---------------------------------
// One block per (chunk,b,h); 4 waves, wave w owns queries q in [w*32,w*32+32).
// S^T = mfma(A=K, B=Q) so lane (l31,hi) holds S[q=R0+l31][64 of 128 keys]
// IN REGISTERS. Softmax is lane-local (one shfl_xor(32) pair-reduce); P is
// normalized in-register, packed to bf16 and fed to PV's A-operand via
// 4 shfl_xor(32) per 16-key step. No P through LDS, no inter-phase barrier:
// waves are independent from the carry barrier to the output barrier.
// 32x32x16 A/B/C-D layouts are HW-verified by the passing gemm_256 (R2/R3).
#define QS 72
#define VT 136
#define OS 72
#define KS_OFF (128 * QS)

__global__ __launch_bounds__(256, 2)
void retention_mfma(const u16* __restrict__ qkv, const void* __restrict__ dec,
                    u16* __restrict__ att) {
    __shared__ u16 qk[2 * 128 * QS];   // Qs | Ks ; Qs rows overlaid by Osm
    __shared__ u16 vt[64 * VT];        // V^T: [d][key]
    __shared__ float kp[64], vp[64], s0f[128], p0i[128];
    u16* Osm = qk;                     // per-wave overlay of OWN Q rows

    const int c = blockIdx.x, b = blockIdx.y, h = blockIdx.z;
    const int t = threadIdx.x;
    const int lane = t & 63, w = t >> 6;
    const int l31 = lane & 31, hi = lane >> 5;
    const int R0 = w * 32;
    const int q = R0 + l31;            // this lane's query row
    const size_t base  = ((size_t)b * L_SEQ) * NQKV + h * D_HEAD;
    const size_t gbase = base + (size_t)(c * CHUNK) * NQKV;
    const size_t obase = (((size_t)b * L_SEQ) + c * CHUNK) * D_MODEL + h * D_HEAD;

    // ---- stage Q, K (row-major) and V (transposed) ----
#pragma unroll
    for (int it = 0; it < 4; it++) {
        const int i = it * 256 + t;
        const int row = i >> 3, seg = i & 7;
        const size_t go = gbase + (size_t)row * NQKV + seg * 8;
        *(uint4*)&qk[row * QS + seg * 8]          = *(const uint4*)(qkv + go);
        *(uint4*)&qk[KS_OFF + row * QS + seg * 8] = *(const uint4*)(qkv + go + 1024);
    }
#pragma unroll
    for (int it = 0; it < 4; it++) {
        const int i = it * 256 + t;
        const int key = i & 127, dseg = i >> 7;
        u16 tmp[8];
        *(uint4*)tmp = *(const uint4*)(qkv + gbase + (size_t)key * NQKV + 2048 + dseg * 8);
#pragma unroll
        for (int j = 0; j < 8; j++)
            vt[(dseg * 8 + j) * VT + key] = tmp[j];
    }
    if (t < 64) {
        const int gl = c * CHUNK - 1;
        float kpv = 0.f, vpv = 0.f;
        if (gl >= 0) {
            const size_t go = base + (size_t)gl * NQKV + t;
            kpv = bf2f(qkv[go + 1024]);
            vpv = bf2f(qkv[go + 2048]);
        }
        kp[t] = kpv; vp[t] = vpv;
    }
    __syncthreads();

    // ---- carry scores s0[row] = q_row . k_prev (2 threads per row) ----
    {
        const int row = t >> 1, half = t & 1;
        const u16* qrow = &qk[row * QS + half * 32];
        float s = 0.f;
#pragma unroll
        for (int d = 0; d < 32; d++) s += bf2f(qrow[d]) * kp[half * 32 + d];
        s += __shfl_xor(s, 1, 64);
        if (half == 0) s0f[row] = s;
    }
    __syncthreads();

    // ---- S^T MFMA: sacc[kt] = K-tile . Q^T  (D[key][q], q = l31) ----
    bf16x8 qf[4];
#pragma unroll
    for (int dks = 0; dks < 4; dks++)
        qf[dks] = *(const bf16x8*)&qk[q * QS + dks * 16 + hi * 8];

    floatx16 sacc[4];
#pragma unroll
    for (int kt = 0; kt < 4; kt++) {
#pragma unroll
        for (int r = 0; r < 16; r++) sacc[kt][r] = 0.f;
#pragma unroll
        for (int dks = 0; dks < 4; dks++) {
            bf16x8 kf = *(const bf16x8*)&qk[KS_OFF + (kt * 32 + l31) * QS
                                            + dks * 16 + hi * 8];
            sacc[kt] = __builtin_amdgcn_mfma_f32_32x32x16_bf16(
                kf, qf[dks], sacc[kt], 0, 0, 0);
        }
    }

    // ---- lane-local softmax over this lane's 64 keys (+partner via shfl) --
    const float dval = load_decay(dec, h);
    const float logd = __logf(dval);
    const float dp = __expf((float)q * logd) * 0.125f;
    const float s0p = s0f[q] * dp;

    float vmax = s0p;
#pragma unroll
    for (int kt = 0; kt < 4; kt++)
#pragma unroll
        for (int r = 0; r < 16; r++) {
            const float v = sacc[kt][r] * dp;
            sacc[kt][r] = v;
            vmax = fmaxf(vmax, v);
        }
    vmax = fmaxf(vmax, __shfl_xor(vmax, 32, 64));

    float lsum = 0.f;
#pragma unroll
    for (int kt = 0; kt < 4; kt++)
#pragma unroll
        for (int r = 0; r < 16; r++) {
            const float e = __expf(sacc[kt][r] - vmax);
            sacc[kt][r] = e;
            lsum += e;
        }
    lsum += __shfl_xor(lsum, 32, 64);
    const float p0 = __expf(s0p - vmax);
    const float inv = 1.0f / (lsum + p0);
#pragma unroll
    for (int kt = 0; kt < 4; kt++)
#pragma unroll
        for (int r = 0; r < 16; r++) sacc[kt][r] *= inv;
    if (hi == 0) p0i[q] = p0 * inv;    // wave-local write, read later in-wave

    // ---- PV: O[q][d] = P̂ . V ; P̂ fed from registers ----
    floatx16 oacc[2];
#pragma unroll
    for (int dt = 0; dt < 2; dt++)
#pragma unroll
        for (int r = 0; r < 16; r++) oacc[dt][r] = 0.f;

#pragma unroll
    for (int s = 0; s < 8; s++) {
        const int kt = s >> 1, rb = (s & 1) * 8;
        // pack pairs: hi=0 holds local keys {0..3,8..11}, hi=1 {4..7,12..15}
        const u32 c0 = pk2(sacc[kt][rb + 0], sacc[kt][rb + 1]);
        const u32 c1 = pk2(sacc[kt][rb + 2], sacc[kt][rb + 3]);
        const u32 c2 = pk2(sacc[kt][rb + 4], sacc[kt][rb + 5]);
        const u32 c3 = pk2(sacc[kt][rb + 6], sacc[kt][rb + 7]);
        const u32 pc0 = (u32)__shfl_xor((int)c0, 32, 64);
        const u32 pc1 = (u32)__shfl_xor((int)c1, 32, 64);
        const u32 pc2 = (u32)__shfl_xor((int)c2, 32, 64);
        const u32 pc3 = (u32)__shfl_xor((int)c3, 32, 64);
        union { uint4 u; bf16x8 v; } aw;
        aw.u.x = hi ? pc2 : c0;        // keys hi*8 + {0,1}
        aw.u.y = hi ? pc3 : c1;        // keys hi*8 + {2,3}
        aw.u.z = hi ? c2 : pc0;        // keys hi*8 + {4,5}
        aw.u.w = hi ? c3 : pc1;        // keys hi*8 + {6,7}
#pragma unroll
        for (int dt = 0; dt < 2; dt++) {
            bf16x8 vf = *(const bf16x8*)&vt[(dt * 32 + l31) * VT
                                            + s * 16 + hi * 8];
            oacc[dt] = __builtin_amdgcn_mfma_f32_32x32x16_bf16(
                aw.v, vf, oacc[dt], 0, 0, 0);
        }
    }

    // ---- epilogue: +carry rank-1, write own rows to Osm (overlay Qs) ----
    // D layout: col = l31 = d, row(reg r) = (r&3)+8*(r>>2)+4*hi (q-local).
#pragma unroll
    for (int dt = 0; dt < 2; dt++) {
        const int d = dt * 32 + l31;
        const float vpc = vp[d];
#pragma unroll
        for (int r = 0; r < 16; r++) {
            const int ql = (r & 3) + 8 * (r >> 2) + 4 * hi;
            const float val = oacc[dt][r] + p0i[R0 + ql] * vpc;
            Osm[(R0 + ql) * OS + d] = f2bf(val);
        }
    }
    __syncthreads();
    // ---- coalesced store: 128 rows x 8 uint4-segments, 4 per thread ----
#pragma unroll
    for (int it = 0; it < 4; it++) {
        const int lin = it * 256 + t;
        const int row = lin >> 3, seg = lin & 7;
        *(uint4*)&att[obase + (size_t)row * D_MODEL + seg * 8] =
            *(const uint4*)&Osm[row * OS + seg * 8];
    }
}

// ---------------------------- launcher -------------------------------------
extern "C" void kernel_launch(void* const* d_in, const int* in_sizes, int n_in,
                              void* d_out, int out_size, void* d_ws, size_t ws_size,
                              hipStream_t stream) {
    const void* x   = d_in[0];
    const void* Wq  = d_in[1];
    const void* bq  = d_in[2];
    const void* Wk  = d_in[3];
    const void* bk  = d_in[4];
    const void* Wv  = d_in[5];
    const void* bv  = d_in[6];
    const void* Wo  = d_in[7];
    const void* bo  = d_in[8];
    const void* dec = d_in[9];
    float* out = (float*)d_out;               // reference output dtype: fp32

    char* ws = (char*)d_ws;
    const size_t mat = (size_t)M_ROWS * D_MODEL * sizeof(u16);   // 33.5 MB
    const size_t wsz = (size_t)D_MODEL * D_MODEL * sizeof(u16);  // 2 MB
    u16* xb   = (u16*)(ws);                   // canonical bf16 x; later att
    u16* qkv  = (u16*)(ws + mat);             // fused [16384][3072]
    u16* WT   = (u16*)(ws + 4 * mat);         // WqT|WkT|WvT|WoT contiguous
    u16* WoT  = WT + 3 * (size_t)D_MODEL * D_MODEL;
    u16* bias = (u16*)(ws + 4 * mat + 4 * wsz);   // bq|bk|bv|bo bf16
    int* flags = (int*)(ws + 4 * mat + 4 * wsz + 8192);

    dim3 tb(256);
    detect_dtypes<<<1, 64, 0, stream>>>(x, Wq, flags);
    convert_x<<<8192, tb, 0, stream>>>(x, flags, xb);
    transpose4<<<dim3(32, 32, 4), tb, 0, stream>>>(
        Wq, Wk, Wv, Wo, flags,
        WT, WT + wsz / 2, WT + wsz, WoT);
    concat_bias<<<16, tb, 0, stream>>>(bq, bk, bv, bo, flags, bias);
    // fused QKV: N=3072 -> 64 row-groups x 12 col-tiles = 768 blocks
    gemm_256<u16><<<dim3(64 * 12), dim3(512), 131072, stream>>>(
        xb, WT, bias, qkv, NQKV);
    retention_mfma<<<dim3(N_CHUNKS, BATCH, N_HEADS), tb, 0, stream>>>(qkv, dec, xb);
    // output projection: N=1024 -> 64 x 4 = 256 blocks
    gemm_256<float><<<dim3(64 * 4), dim3(512), 131072, stream>>>(
        xb, WoT, bias + 3072, out, D_MODEL);
}